// Round 1
// baseline (2217.505 us; speedup 1.0000x reference)
//
#include <hip/hip_runtime.h>

// ---------------- degree / dinv ----------------

__global__ void deg_init_k(float* __restrict__ deg, int n) {
  int i = blockIdx.x * blockDim.x + threadIdx.x;
  if (i < n) deg[i] = 1.0f;  // self-loop
}

__global__ void deg_count_k(const int* __restrict__ dst, float* __restrict__ deg, int E) {
  int e = blockIdx.x * blockDim.x + threadIdx.x;
  if (e < E) atomicAdd(&deg[dst[e]], 1.0f);
}

__global__ void dinv_k(float* __restrict__ d, int n) {
  int i = blockIdx.x * blockDim.x + threadIdx.x;
  if (i < n) d[i] = rsqrtf(d[i]);  // deg >= 1 always
}

// ---------------- GEMM: C[n,NC] = (RELU?relu(X):X)[n,128] @ W[128,NC] ----------------
// W staged fully in LDS. Each thread: 4 rows x 4 cols accumulators.
// LDS traffic: 1 ds_read_b128 per 16 FMAs.

template<int NC, bool RELU>
__global__ __launch_bounds__(256) void gemm_k(const float* __restrict__ X,
                                              const float* __restrict__ W,
                                              float* __restrict__ C, int n) {
  constexpr int K   = 128;
  constexpr int CG  = NC / 4;     // lanes covering the NC columns (float4 each)
  constexpr int NG  = 256 / CG;   // row-groups per block
  constexpr int RPT = 4;          // rows per thread
  constexpr int RPI = NG * RPT;   // rows per block

  __shared__ float sW[K * NC];
  for (int i = threadIdx.x; i < K * NC / 4; i += 256)
    reinterpret_cast<float4*>(sW)[i] = reinterpret_cast<const float4*>(W)[i];
  __syncthreads();

  const int rg   = threadIdx.x / CG;
  const int c    = threadIdx.x % CG;
  const int row0 = blockIdx.x * RPI + rg * RPT;

  float acc[RPT][4];
#pragma unroll
  for (int r = 0; r < RPT; ++r)
#pragma unroll
    for (int j = 0; j < 4; ++j) acc[r][j] = 0.0f;

  const float4* X4 = reinterpret_cast<const float4*>(X);
  const float4* W4 = reinterpret_cast<const float4*>(sW);

  for (int k4 = 0; k4 < K / 4; ++k4) {
    float xq[RPT][4];
#pragma unroll
    for (int r = 0; r < RPT; ++r) {
      float4 v = make_float4(0.f, 0.f, 0.f, 0.f);
      if (row0 + r < n) v = X4[(size_t)(row0 + r) * (K / 4) + k4];
      if (RELU) {
        v.x = fmaxf(v.x, 0.f); v.y = fmaxf(v.y, 0.f);
        v.z = fmaxf(v.z, 0.f); v.w = fmaxf(v.w, 0.f);
      }
      xq[r][0] = v.x; xq[r][1] = v.y; xq[r][2] = v.z; xq[r][3] = v.w;
    }
#pragma unroll
    for (int kk = 0; kk < 4; ++kk) {
      float4 wv = W4[((k4 * 4 + kk) * NC) / 4 + c];
#pragma unroll
      for (int r = 0; r < RPT; ++r) {
        acc[r][0] += xq[r][kk] * wv.x;
        acc[r][1] += xq[r][kk] * wv.y;
        acc[r][2] += xq[r][kk] * wv.z;
        acc[r][3] += xq[r][kk] * wv.w;
      }
    }
  }

#pragma unroll
  for (int r = 0; r < RPT; ++r) {
    if (row0 + r < n) {
      float4 o = make_float4(acc[r][0], acc[r][1], acc[r][2], acc[r][3]);
      reinterpret_cast<float4*>(C)[(size_t)(row0 + r) * (NC / 4) + c] = o;
    }
  }
}

// ---------------- self-loop + bias init: out[i] = h[i]*dinv[i]^2 + b ----------------

template<int D>
__global__ void selfloop_bias_k(const float* __restrict__ h, const float* __restrict__ dinv,
                                const float* __restrict__ bias, float* __restrict__ out,
                                int n) {
  long long t = (long long)blockIdx.x * blockDim.x + threadIdx.x;
  long long total = (long long)n * (D / 4);
  if (t >= total) return;
  int i  = (int)(t / (D / 4));
  int d4 = (int)(t % (D / 4));
  float w = dinv[i];
  w = w * w;
  float4 v = reinterpret_cast<const float4*>(h)[t];
  float4 b = reinterpret_cast<const float4*>(bias)[d4];
  float4 o = make_float4(v.x * w + b.x, v.y * w + b.y, v.z * w + b.z, v.w * w + b.w);
  reinterpret_cast<float4*>(out)[t] = o;
}

// ---------------- edge scatter: out[dst] += h[src] * (dinv[src]*dinv[dst]) ----------------
// D/4 lanes per edge; float4 gather (coalesced 512B/256B per edge), 4 atomics per lane.

template<int D>
__global__ void scatter_k(const float* __restrict__ h, const int* __restrict__ src,
                          const int* __restrict__ dst, const float* __restrict__ dinv,
                          float* __restrict__ out, int E) {
  constexpr int LPE = D / 4;
  long long t = (long long)blockIdx.x * blockDim.x + threadIdx.x;
  long long e = t / LPE;
  if (e >= E) return;
  int d4 = (int)(t % LPE);
  int s  = src[e];
  int dd = dst[e];
  float nw = dinv[s] * dinv[dd];
  float4 v = reinterpret_cast<const float4*>(h + (size_t)s * D)[d4];
  float* o = out + (size_t)dd * D + (size_t)d4 * 4;
  atomicAdd(o + 0, v.x * nw);
  atomicAdd(o + 1, v.y * nw);
  atomicAdd(o + 2, v.z * nw);
  atomicAdd(o + 3, v.w * nw);
}

// ---------------- launch ----------------

extern "C" void kernel_launch(void* const* d_in, const int* in_sizes, int n_in,
                              void* d_out, int out_size, void* d_ws, size_t ws_size,
                              hipStream_t stream) {
  const float* x  = (const float*)d_in[0];
  const int*   ei = (const int*)d_in[1];
  const float* W1 = (const float*)d_in[2];
  const float* b1 = (const float*)d_in[3];
  const float* W2 = (const float*)d_in[4];
  const float* b2 = (const float*)d_in[5];

  const int n = in_sizes[0] / 128;   // 50000
  const int E = in_sizes[1] / 2;     // 800000
  const int* src = ei;               // edge_index[0]
  const int* dst = ei + E;           // edge_index[1]
  float* out = (float*)d_out;

  // workspace: dinv[n] | h1[n*128] (reused as h3[n*64]) | agg1[n*128]
  float* dinv = (float*)d_ws;
  float* h1   = dinv + n;
  float* agg1 = h1 + (size_t)n * 128;
  float* h3   = h1;  // reuse after scatter1 consumes h1

  // degree -> dinv
  deg_init_k<<<(n + 255) / 256, 256, 0, stream>>>(dinv, n);
  deg_count_k<<<(E + 255) / 256, 256, 0, stream>>>(dst, dinv, E);
  dinv_k<<<(n + 255) / 256, 256, 0, stream>>>(dinv, n);

  // layer 1: h1 = x @ W1
  gemm_k<128, false><<<(n + 31) / 32, 256, 0, stream>>>(x, W1, h1, n);
  // agg1 = h1*dinv^2 + b1  (self-loop + bias)
  {
    long long t = (long long)n * 32;
    selfloop_bias_k<128><<<(int)((t + 255) / 256), 256, 0, stream>>>(h1, dinv, b1, agg1, n);
  }
  // agg1[dst] += h1[src]*norm
  {
    long long t = (long long)E * 32;
    scatter_k<128><<<(int)((t + 255) / 256), 256, 0, stream>>>(h1, src, dst, dinv, agg1, E);
  }

  // layer 2: h3 = relu(agg1) @ W2   (relu fused into load; bias b1 already inside agg1)
  gemm_k<64, true><<<(n + 63) / 64, 256, 0, stream>>>(agg1, W2, h3, n);
  // out = h3*dinv^2 + b2
  {
    long long t = (long long)n * 16;
    selfloop_bias_k<64><<<(int)((t + 255) / 256), 256, 0, stream>>>(h3, dinv, b2, out, n);
  }
  // out[dst] += h3[src]*norm
  {
    long long t = (long long)E * 16;
    scatter_k<64><<<(int)((t + 255) / 256), 256, 0, stream>>>(h3, src, dst, dinv, out, E);
  }
}

// Round 2
// 453.406 us; speedup vs baseline: 4.8908x; 4.8908x over previous
//
#include <hip/hip_runtime.h>

// ---------------- CSR build ----------------

__global__ void zero_int_k(int* __restrict__ p, int n) {
  int i = blockIdx.x * blockDim.x + threadIdx.x;
  if (i < n) p[i] = 0;
}

__global__ void deg_count_k(const int* __restrict__ dst, int* __restrict__ cnt, int E) {
  int e = blockIdx.x * blockDim.x + threadIdx.x;
  if (e < E) atomicAdd(&cnt[dst[e]], 1);
}

__global__ void dinv_k(const int* __restrict__ cnt, float* __restrict__ dinv, int n) {
  int i = blockIdx.x * blockDim.x + threadIdx.x;
  if (i < n) dinv[i] = rsqrtf((float)(cnt[i] + 1));  // +1 self-loop
}

// exclusive scan of cnt[n] -> rowstart[n+1], also copy into cursor[n]. single block.
__global__ __launch_bounds__(1024) void scan_k(const int* __restrict__ cnt,
                                               int* __restrict__ rowstart,
                                               int* __restrict__ cursor, int n, int E) {
  __shared__ int part[1024];
  const int t = threadIdx.x;
  const int chunk = (n + 1023) / 1024;
  const int lo = t * chunk;
  const int hi = min(n, lo + chunk);
  int s = 0;
  for (int i = lo; i < hi; ++i) s += cnt[i];
  part[t] = s;
  __syncthreads();
  for (int off = 1; off < 1024; off <<= 1) {
    int v = (t >= off) ? part[t - off] : 0;
    __syncthreads();
    part[t] += v;
    __syncthreads();
  }
  int running = (t == 0) ? 0 : part[t - 1];
  for (int i = lo; i < hi; ++i) {
    rowstart[i] = running;
    cursor[i] = running;
    running += cnt[i];
  }
  if (t == 0) rowstart[n] = E;
}

__global__ void fill_k(const int* __restrict__ src, const int* __restrict__ dst,
                       int* __restrict__ cursor, int* __restrict__ srcs, int E) {
  int e = blockIdx.x * blockDim.x + threadIdx.x;
  if (e >= E) return;
  int d = dst[e];
  int pos = atomicAdd(&cursor[d], 1);
  srcs[pos] = src[e];
}

// ---------------- GEMM: C[n,NC] = (RELU?relu(X):X)[n,128] @ W[128,NC] ----------------

template<int NC, bool RELU>
__global__ __launch_bounds__(256) void gemm_k(const float* __restrict__ X,
                                              const float* __restrict__ W,
                                              float* __restrict__ C, int n) {
  constexpr int K   = 128;
  constexpr int CG  = NC / 4;
  constexpr int NG  = 256 / CG;
  constexpr int RPT = 4;
  constexpr int RPI = NG * RPT;

  __shared__ float sW[K * NC];
  for (int i = threadIdx.x; i < K * NC / 4; i += 256)
    reinterpret_cast<float4*>(sW)[i] = reinterpret_cast<const float4*>(W)[i];
  __syncthreads();

  const int rg   = threadIdx.x / CG;
  const int c    = threadIdx.x % CG;
  const int row0 = blockIdx.x * RPI + rg * RPT;

  float acc[RPT][4];
#pragma unroll
  for (int r = 0; r < RPT; ++r)
#pragma unroll
    for (int j = 0; j < 4; ++j) acc[r][j] = 0.0f;

  const float4* X4 = reinterpret_cast<const float4*>(X);
  const float4* W4 = reinterpret_cast<const float4*>(sW);

  for (int k4 = 0; k4 < K / 4; ++k4) {
    float xq[RPT][4];
#pragma unroll
    for (int r = 0; r < RPT; ++r) {
      float4 v = make_float4(0.f, 0.f, 0.f, 0.f);
      if (row0 + r < n) v = X4[(size_t)(row0 + r) * (K / 4) + k4];
      if (RELU) {
        v.x = fmaxf(v.x, 0.f); v.y = fmaxf(v.y, 0.f);
        v.z = fmaxf(v.z, 0.f); v.w = fmaxf(v.w, 0.f);
      }
      xq[r][0] = v.x; xq[r][1] = v.y; xq[r][2] = v.z; xq[r][3] = v.w;
    }
#pragma unroll
    for (int kk = 0; kk < 4; ++kk) {
      float4 wv = W4[((k4 * 4 + kk) * NC) / 4 + c];
#pragma unroll
      for (int r = 0; r < RPT; ++r) {
        acc[r][0] += xq[r][kk] * wv.x;
        acc[r][1] += xq[r][kk] * wv.y;
        acc[r][2] += xq[r][kk] * wv.z;
        acc[r][3] += xq[r][kk] * wv.w;
      }
    }
  }

#pragma unroll
  for (int r = 0; r < RPT; ++r) {
    if (row0 + r < n) {
      float4 o = make_float4(acc[r][0], acc[r][1], acc[r][2], acc[r][3]);
      reinterpret_cast<float4*>(C)[(size_t)(row0 + r) * (NC / 4) + c] = o;
    }
  }
}

// ---------------- gather-reduce per dst node ----------------
// out[i] = (sum_{j in row(i)} h[srcs[j]] * dinv[srcs[j]]) * dinv[i]
//          + h[i] * dinv[i]^2 + bias
// D/4 lanes per node, each owning one float4 slice; edge reads are coalesced
// 512B (D=128) / 256B (D=64) blocks.

template<int D>
__global__ __launch_bounds__(256) void gather_k(const float* __restrict__ h,
                                                const int* __restrict__ rowstart,
                                                const int* __restrict__ srcs,
                                                const float* __restrict__ dinv,
                                                const float* __restrict__ bias,
                                                float* __restrict__ out, int n) {
  constexpr int L = D / 4;
  int t = blockIdx.x * 256 + threadIdx.x;
  int node = t / L;
  int d4 = t % L;
  if (node >= n) return;

  const int r0 = rowstart[node];
  const int r1 = rowstart[node + 1];
  const float4* h4 = reinterpret_cast<const float4*>(h);

  float4 acc = make_float4(0.f, 0.f, 0.f, 0.f);
  for (int j = r0; j < r1; ++j) {
    int s = srcs[j];
    float w = dinv[s];
    float4 v = h4[(size_t)s * L + d4];
    acc.x += v.x * w; acc.y += v.y * w; acc.z += v.z * w; acc.w += v.w * w;
  }

  const float di = dinv[node];
  const float di2 = di * di;
  float4 self = h4[(size_t)node * L + d4];
  float4 b = reinterpret_cast<const float4*>(bias)[d4];
  float4 o;
  o.x = acc.x * di + self.x * di2 + b.x;
  o.y = acc.y * di + self.y * di2 + b.y;
  o.z = acc.z * di + self.z * di2 + b.z;
  o.w = acc.w * di + self.w * di2 + b.w;
  reinterpret_cast<float4*>(out)[(size_t)node * L + d4] = o;
}

// ---------------- launch ----------------

extern "C" void kernel_launch(void* const* d_in, const int* in_sizes, int n_in,
                              void* d_out, int out_size, void* d_ws, size_t ws_size,
                              hipStream_t stream) {
  const float* x  = (const float*)d_in[0];
  const int*   ei = (const int*)d_in[1];
  const float* W1 = (const float*)d_in[2];
  const float* b1 = (const float*)d_in[3];
  const float* W2 = (const float*)d_in[4];
  const float* b2 = (const float*)d_in[5];

  const int n = in_sizes[0] / 128;   // 50000
  const int E = in_sizes[1] / 2;     // 800000
  const int* src = ei;
  const int* dst = ei + E;
  float* out = (float*)d_out;

  // workspace layout (floats/ints, 4B each):
  // dinv[n] | cnt[n] | rowstart[n+1] | cursor[n] | srcs[E] | h1[n*128] | agg1[n*128]
  float* dinv     = (float*)d_ws;
  int*   cnt      = (int*)(dinv + n);
  int*   rowstart = cnt + n;
  int*   cursor   = rowstart + (n + 1);
  int*   srcs     = cursor + n;
  float* h1       = (float*)(srcs + E);
  float* agg1     = h1 + (size_t)n * 128;
  float* h3       = h1;  // reuse after gather1 consumed h1

  // ---- CSR build (shared by both layers) ----
  zero_int_k<<<(n + 255) / 256, 256, 0, stream>>>(cnt, n);
  deg_count_k<<<(E + 255) / 256, 256, 0, stream>>>(dst, cnt, E);
  dinv_k<<<(n + 255) / 256, 256, 0, stream>>>(cnt, dinv, n);
  scan_k<<<1, 1024, 0, stream>>>(cnt, rowstart, cursor, n, E);
  fill_k<<<(E + 255) / 256, 256, 0, stream>>>(src, dst, cursor, srcs, E);

  // ---- layer 1 ----
  gemm_k<128, false><<<(n + 31) / 32, 256, 0, stream>>>(x, W1, h1, n);
  {
    long long t = (long long)n * 32;
    gather_k<128><<<(int)((t + 255) / 256), 256, 0, stream>>>(h1, rowstart, srcs, dinv, b1, agg1, n);
  }

  // ---- layer 2 ----
  gemm_k<64, true><<<(n + 63) / 64, 256, 0, stream>>>(agg1, W2, h3, n);
  {
    long long t = (long long)n * 16;
    gather_k<64><<<(int)((t + 255) / 256), 256, 0, stream>>>(h3, rowstart, srcs, dinv, b2, out, n);
  }
}